// Round 22
// baseline (43.232 us; speedup 1.0000x reference)
//
#include <hip/hip_runtime.h>
#include <hip/hip_bf16.h>
#include <math.h>

#define NTILES 64
#define TPC 8
#define NCLUST 8
#define GRID_SZ 16
#define DIM 512
#define DHID 128
#define NTOK 2048
#define LN_EPS 1e-5f
#define TB 16             // tokens per chunk == MFMA M-tile
#define NCHUNK_MAX 192    // sum ceil(cnt/16) <= 128 + 60 < 192 = 8*24

typedef __attribute__((ext_vector_type(8))) short bf16x8;
typedef __attribute__((ext_vector_type(4))) unsigned short u16x4;
typedef __attribute__((ext_vector_type(4))) float f32x4;
typedef unsigned long long u64;

static __device__ __forceinline__ unsigned short bf16bits(float f) {
    union { __hip_bfloat16 h; unsigned short s; } u;
    u.h = __float2bfloat16(f);
    return u.s;
}

static __device__ __forceinline__ bf16x8 cvt8v(float4 a, float4 b) {
    float e[8] = {a.x, a.y, a.z, a.w, b.x, b.y, b.z, b.w};
    bf16x8 v;
    #pragma unroll
    for (int i = 0; i < 8; ++i) v[i] = (short)bf16bits(e[i]);
    return v;
}

static __device__ __forceinline__ u64 maj3(u64 a, u64 b, u64 c) {
    return (a & b) | (c & (a ^ b));
}

// in-wave self-routing: chunk id cb -> (t, base, m). false if no work.
static __device__ __forceinline__ bool route_chunk(const int* counts, int lane, int cb,
                                                   int& t, int& base, int& m) {
    int cnt_l = counts[lane];
    int nck = (cnt_l + TB - 1) / TB;
    int pre = nck;
    #pragma unroll
    for (int off = 1; off < 64; off <<= 1) {
        int u = __shfl_up(pre, off);
        if (lane >= off) pre += u;
    }
    int total = __shfl(pre, 63);
    pre -= nck;
    if (cb >= total) return false;
    u64 msk = __ballot(cb >= pre && cb < pre + nck);
    t = (int)__builtin_ctzll(msk);
    base = (cb - __shfl(pre, t)) * TB;
    m = min(TB, __shfl(cnt_l, t) - base);
    return true;
}

// K1: 512 BALANCED blocks x 512 threads, no cross-block communication:
//   0..255  : Wd COLUMN-quarter (t=bid>>2, q=bid&3): all 128 rows x 128 cols.
//             Column sums complete locally -> LDS combine -> ballot -> 2 tbits words.
//   256..511: LayerNorm (8 tokens/block) -> bf16 xn + sign ballots xbits
// (Wu copy moved to K2 where idle BW exists.) Normal stores (R18 lesson).
__global__ __launch_bounds__(512) void k_prep(const float* __restrict__ x,
                                              const float* __restrict__ gamma,
                                              const float* __restrict__ beta,
                                              const float* __restrict__ Wd,
                                              unsigned short* __restrict__ wd_b,
                                              unsigned short* __restrict__ xn_b,
                                              u64* __restrict__ tbits,
                                              u64* __restrict__ xbits,
                                              int* __restrict__ counts) {
    int bid = blockIdx.x;
    int tid = threadIdx.x;
    int lane = tid & 63;
    int wv = tid >> 6;
    if (bid < 256) {
        int t = bid >> 2, q = bid & 3;     // q = column quarter (cols q*128 .. q*128+127)
        if (bid == 0 && tid < NTILES) counts[tid] = 0;
        int r0 = tid >> 5;                 // row slice 0..15 -> rows r0*8 .. r0*8+7
        int c4 = tid & 31;                 // col group: cols q*128 + c4*4 .. +3
        const float* wp = Wd + ((size_t)t * DHID + r0 * 8) * DIM + q * 128 + c4 * 4;
        unsigned short* bp = wd_b + ((size_t)t * DHID + r0 * 8) * DIM + q * 128 + c4 * 4;
        float4 v[8];
        #pragma unroll
        for (int k = 0; k < 8; ++k) v[k] = *(const float4*)(wp + (size_t)k * DIM);
        float4 a = {0.f, 0.f, 0.f, 0.f};
        #pragma unroll
        for (int k = 0; k < 8; ++k) {
            u16x4 h = {bf16bits(v[k].x), bf16bits(v[k].y), bf16bits(v[k].z), bf16bits(v[k].w)};
            *(u16x4*)(bp + (size_t)k * DIM) = h;
            a.x += v[k].x; a.y += v[k].y; a.z += v[k].z; a.w += v[k].w;
        }
        __shared__ float ps[16][128];
        *(float4*)&ps[r0][c4 * 4] = a;
        __syncthreads();
        if (tid < 128) {                   // waves 0,1: column totals + ballot
            float s = 0.f;
            #pragma unroll
            for (int k = 0; k < 16; ++k) s += ps[k][tid];
            u64 b = __ballot(s < 0.f);     // wave wv covers cols q*128 + wv*64 + lane
            if (lane == 0) tbits[t * 8 + q * 2 + wv] = b;
        }
    } else {
        int n = (bid - 256) * 8 + wv;
        const float* xr = x + (size_t)n * DIM;
        float v[8];
        float sum = 0.f;
        #pragma unroll
        for (int j = 0; j < 8; ++j) { float t = xr[lane + 64 * j]; v[j] = t; sum += t; }
        #pragma unroll
        for (int off = 32; off; off >>= 1) sum += __shfl_xor(sum, off);
        float mu = sum * (1.f / DIM);
        float sq = 0.f;
        #pragma unroll
        for (int j = 0; j < 8; ++j) { float t = v[j] - mu; sq += t * t; }
        #pragma unroll
        for (int off = 32; off; off >>= 1) sq += __shfl_xor(sq, off);
        float rs = rsqrtf(sq * (1.f / DIM) + LN_EPS);
        #pragma unroll
        for (int j = 0; j < 8; ++j) {
            int d = lane + 64 * j;
            float xv = (v[j] - mu) * rs * gamma[d] + beta[d];
            unsigned short us = bf16bits(xv);
            xn_b[(size_t)n * DIM + d] = us;
            u64 bb = __ballot((us & 0x8000u) != 0 && (us & 0x7fffu) != 0);
            if (lane == 0) xbits[n * 8 + j] = bb;
        }
    }
}

// K2: routing (from xbits, wave-uniform scalar loads) FUSED with Wu->bf16 copy.
// 512 blocks x 256 threads. Wu float4 loads issued FIRST; routing's shuffle/
// popcount latency executes under the load stream; cvt+store after.
__global__ __launch_bounds__(256) void k_route(const u64* __restrict__ xbits,
                                               const u64* __restrict__ tbits,
                                               const float* __restrict__ Wu,
                                               unsigned short* __restrict__ wu_b,
                                               int* __restrict__ counts,
                                               int* __restrict__ list) {
    int bid = blockIdx.x;
    int tid = threadIdx.x;
    int lane = tid & 63;
    int wv = tid >> 6;

    // issue Wu copy loads first (32 floats/thread = 8 float4, independent)
    size_t basei = (size_t)bid * 8192 + (size_t)tid * 8;
    float4 wl[8];
    #pragma unroll
    for (int k = 0; k < 4; ++k) {
        wl[2 * k]     = *(const float4*)(Wu + basei + (size_t)k * 2048);
        wl[2 * k + 1] = *(const float4*)(Wu + basei + (size_t)k * 2048 + 4);
    }

    // routing for token n (math overlaps the loads above)
    int n = bid * 4 + wv;
    u64 xb[8];
    #pragma unroll
    for (int j = 0; j < 8; ++j) xb[j] = xbits[n * 8 + j];   // wave-uniform
    const u64* tb = tbits + lane * 8;
    int ts = 0;
    #pragma unroll
    for (int j = 0; j < 8; ++j) ts += __popcll(xb[j] ^ tb[j]);
    int tscore = DIM - 2 * ts;

    int c = lane >> 3, jw = lane & 7;
    u64 x0 = tbits[(c * TPC + 0) * 8 + jw], x1 = tbits[(c * TPC + 1) * 8 + jw];
    u64 x2 = tbits[(c * TPC + 2) * 8 + jw], x3 = tbits[(c * TPC + 3) * 8 + jw];
    u64 x4 = tbits[(c * TPC + 4) * 8 + jw], x5 = tbits[(c * TPC + 5) * 8 + jw];
    u64 x6 = tbits[(c * TPC + 6) * 8 + jw], x7 = tbits[(c * TPC + 7) * 8 + jw];
    u64 s0 = x0 ^ x1 ^ x2, c0 = maj3(x0, x1, x2);
    u64 s1 = x3 ^ x4 ^ x5, c1 = maj3(x3, x4, x5);
    u64 s2 = x6 ^ x7,      c2 = x6 & x7;
    u64 t0 = s0 ^ s1 ^ s2, t1 = maj3(s0, s1, s2);
    u64 p = c0 ^ c1, q = c0 & c1;
    u64 r = c2 ^ t1, s_ = c2 & t1;
    u64 S0 = p ^ r, car = p & r;
    u64 W0 = (q ^ s_) ^ car;
    u64 W1 = (q & s_) | (car & (q ^ s_));
    u64 cbit = W1 | (W0 & (S0 | t0));
    u64 cmsk = ~(W0 & ~W1 & ~S0 & ~t0);
    int psc = __popcll(cmsk) - 2 * __popcll((xb[jw] ^ cbit) & cmsk);
    psc += __shfl_xor(psc, 1);
    psc += __shfl_xor(psc, 2);
    psc += __shfl_xor(psc, 4);

    int bc = 0, best = __shfl(psc, 0);
    #pragma unroll
    for (int k = 1; k < NCLUST; ++k) {
        int v = __shfl(psc, k * 8);
        if (v > best) { best = v; bc = k; }
    }
    int bt = bc * TPC, bts = __shfl(tscore, bc * TPC);
    #pragma unroll
    for (int k = 1; k < TPC; ++k) {
        int v = __shfl(tscore, bc * TPC + k);
        if (v > bts) { bts = v; bt = bc * TPC + k; }
    }
    if (lane == 0) {
        int slot = atomicAdd(&counts[bt], 1);
        list[(size_t)bt * NTOK + slot] = n;
    }

    // complete Wu copy: cvt + store
    #pragma unroll
    for (int k = 0; k < 4; ++k)
        *(bf16x8*)(wu_b + basei + (size_t)k * 2048) = cvt8v(wl[2 * k], wl[2 * k + 1]);
}

// K3: fused down+spline+up, deep-prefetch variant (unchanged from R19/R21).
__global__ __launch_bounds__(512, 1) void k_ffn(const float* __restrict__ x,
                                                const unsigned short* __restrict__ xn_b,
                                                const unsigned short* __restrict__ wd_b,
                                                const float* __restrict__ sb,
                                                const float* __restrict__ ss,
                                                const unsigned short* __restrict__ wu_b,
                                                const float* __restrict__ scale,
                                                const int* __restrict__ counts,
                                                const int* __restrict__ list,
                                                float* __restrict__ out) {
    int tid = threadIdx.x;
    int lane = tid & 63;
    int wv = tid >> 6;
    int cb = ((int)blockIdx.x & 7) * (NCHUNK_MAX / 8) + ((int)blockIdx.x >> 3);
    int t, base, m;
    if (!route_chunk(counts, lane, cb, t, base, m)) return;   // block-uniform exit

    __shared__ __align__(16) unsigned short hsl[TB * DHID];   // bf16, XOR-swizzled

    int mrow = lane & 15;
    int ko = (lane >> 4) * 8;
    int tokm = list[(size_t)t * NTOK + base + min(mrow, m - 1)];

    // ---- down: load ALL operands first (32 b128 in flight), then MFMA ----
    const unsigned short* xr = xn_b + (size_t)tokm * DIM;
    const unsigned short* wr = wd_b + ((size_t)t * DHID + wv * 16 + mrow) * DIM;
    bf16x8 wreg[16], areg[16];
    #pragma unroll
    for (int kk = 0; kk < 16; ++kk) {
        int d = kk * 32 + ko;
        wreg[kk] = *(const bf16x8*)(wr + d);
        areg[kk] = *(const bf16x8*)(xr + d);
    }
    f32x4 acc0 = {0.f, 0.f, 0.f, 0.f}, acc1 = acc0;
    #pragma unroll
    for (int kk = 0; kk < 8; ++kk) {
        acc0 = __builtin_amdgcn_mfma_f32_16x16x32_bf16(areg[2 * kk], wreg[2 * kk], acc0, 0, 0, 0);
        acc1 = __builtin_amdgcn_mfma_f32_16x16x32_bf16(areg[2 * kk + 1], wreg[2 * kk + 1], acc1, 0, 0, 0);
    }
    f32x4 acc = acc0 + acc1;

    // prefetch ALL up-phase Wu-bf16 rows (16 b128) before spline + barrier
    bf16x8 wupf[16];
    #pragma unroll
    for (int nt = 0; nt < 4; ++nt) {
        const unsigned short* wru = wu_b + ((size_t)t * DIM + wv * 64 + nt * 16 + mrow) * DHID;
        #pragma unroll
        for (int kk = 0; kk < 4; ++kk)
            wupf[nt * 4 + kk] = *(const bf16x8*)(wru + kk * 32 + ko);
    }

    // prefetch residual x gather (16 scalar f32 per thread; rows tr, cols d)
    int tokr[4];
    #pragma unroll
    for (int r = 0; r < 4; ++r) tokr[r] = __shfl(tokm, (lane >> 4) * 4 + r);
    float xpf[4][4];
    #pragma unroll
    for (int r = 0; r < 4; ++r) {
        #pragma unroll
        for (int nt = 0; nt < 4; ++nt)
            xpf[r][nt] = x[(size_t)tokr[r] * DIM + wv * 64 + nt * 16 + mrow];
    }

    // spline on C fragments -> LDS (rows tr>=m hold duplicated last token: valid bytes)
    int dh = wv * 16 + mrow;
    const float* sbt = sb + ((size_t)t * DHID + dh) * GRID_SZ;
    const float* sst = ss + ((size_t)t * DHID + dh) * GRID_SZ;
    #pragma unroll
    for (int r = 0; r < 4; ++r) {
        int tr = (lane >> 4) * 4 + r;
        float h = acc[r];
        float hn = 1.f / (1.f + expf(-h));
        float g = hn * (float)GRID_SZ;
        int idx = (int)g;
        idx = idx > GRID_SZ - 1 ? GRID_SZ - 1 : idx;
        float lp = g - (float)idx;
        float val = sbt[idx] + sst[idx] * lp;
        hsl[(tr * DHID + dh) ^ ((tr & 7) << 3)] = bf16bits(val);
    }
    __syncthreads();

    // ---- up: d-slice wv (4 independent n-tiles x 4 MFMA, K=128) ----
    float sc_t = scale[t];
    bf16x8 a2[4];
    #pragma unroll
    for (int kk = 0; kk < 4; ++kk)
        a2[kk] = *(const bf16x8*)&hsl[(mrow * DHID + kk * 32 + ko) ^ ((mrow & 7) << 3)];
    #pragma unroll
    for (int nt = 0; nt < 4; ++nt) {
        int d = wv * 64 + nt * 16 + mrow;
        f32x4 au = {0.f, 0.f, 0.f, 0.f};
        #pragma unroll
        for (int kk = 0; kk < 4; ++kk)
            au = __builtin_amdgcn_mfma_f32_16x16x32_bf16(a2[kk], wupf[nt * 4 + kk], au, 0, 0, 0);
        #pragma unroll
        for (int r = 0; r < 4; ++r) {
            int tr = (lane >> 4) * 4 + r;
            if (tr < m) {
                size_t o = (size_t)tokr[r] * DIM + d;
                out[o] = xpf[r][nt] + au[r] * sc_t;
            }
        }
    }
}

extern "C" void kernel_launch(void* const* d_in, const int* in_sizes, int n_in,
                              void* d_out, int out_size, void* d_ws, size_t ws_size,
                              hipStream_t stream) {
    const float* x     = (const float*)d_in[0];
    const float* gamma = (const float*)d_in[1];
    const float* beta  = (const float*)d_in[2];
    const float* Wd    = (const float*)d_in[3];
    const float* sb    = (const float*)d_in[4];
    const float* ss    = (const float*)d_in[5];
    const float* Wu    = (const float*)d_in[6];
    const float* scale = (const float*)d_in[7];
    float* out = (float*)d_out;

    // workspace layout
    u64*   tbits         = (u64*)d_ws;                             // 64*8 u64 = 4 KB
    u64*   xbits         = tbits + NTILES * 8;                     // 2048*8 u64 = 128 KB
    int*   counts        = (int*)(xbits + (size_t)NTOK * 8);       // 64 ints
    int*   list          = counts + NTILES;                        // 128K ints
    unsigned short* xn_b = (unsigned short*)(list + (size_t)NTILES * NTOK);  // 1M u16
    unsigned short* wd_b = xn_b + (size_t)NTOK * DIM;              // 4.19M u16
    unsigned short* wu_b = wd_b + (size_t)NTILES * DHID * DIM;     // 4.19M u16

    k_prep<<<512, 512, 0, stream>>>(x, gamma, beta, Wd, wd_b, xn_b, tbits, xbits, counts);
    k_route<<<NTOK / 4, 256, 0, stream>>>(xbits, tbits, Wu, wu_b, counts, list);
    k_ffn<<<NCHUNK_MAX, 512, 0, stream>>>(x, xn_b, wd_b, sb, ss, wu_b, scale, counts, list, out);
}

// Round 23
// 41.830 us; speedup vs baseline: 1.0335x; 1.0335x over previous
//
#include <hip/hip_runtime.h>
#include <hip/hip_bf16.h>
#include <math.h>

#define NTILES 64
#define TPC 8
#define NCLUST 8
#define GRID_SZ 16
#define DIM 512
#define DHID 128
#define NTOK 2048
#define LN_EPS 1e-5f
#define TB 16             // tokens per chunk == MFMA M-tile
#define NCHUNK_MAX 192    // sum ceil(cnt/16) <= 128 + 60 < 192 = 8*24

typedef __attribute__((ext_vector_type(8))) short bf16x8;
typedef __attribute__((ext_vector_type(4))) unsigned short u16x4;
typedef __attribute__((ext_vector_type(4))) float f32x4;
typedef unsigned long long u64;

static __device__ __forceinline__ unsigned short bf16bits(float f) {
    union { __hip_bfloat16 h; unsigned short s; } u;
    u.h = __float2bfloat16(f);
    return u.s;
}

static __device__ __forceinline__ bf16x8 cvt8(const float* p) {
    float4 a = *(const float4*)p;
    float4 b = *(const float4*)(p + 4);
    float e[8] = {a.x, a.y, a.z, a.w, b.x, b.y, b.z, b.w};
    bf16x8 v;
    #pragma unroll
    for (int i = 0; i < 8; ++i) v[i] = (short)bf16bits(e[i]);
    return v;
}

static __device__ __forceinline__ u64 maj3(u64 a, u64 b, u64 c) {
    return (a & b) | (c & (a ^ b));
}

// in-wave self-routing: chunk id cb -> (t, base, m). false if no work.
static __device__ __forceinline__ bool route_chunk(const int* counts, int lane, int cb,
                                                   int& t, int& base, int& m) {
    int cnt_l = counts[lane];
    int nck = (cnt_l + TB - 1) / TB;
    int pre = nck;
    #pragma unroll
    for (int off = 1; off < 64; off <<= 1) {
        int u = __shfl_up(pre, off);
        if (lane >= off) pre += u;
    }
    int total = __shfl(pre, 63);
    pre -= nck;
    if (cb >= total) return false;
    u64 msk = __ballot(cb >= pre && cb < pre + nck);
    t = (int)__builtin_ctzll(msk);
    base = (cb - __shfl(pre, t)) * TB;
    m = min(TB, __shfl(cnt_l, t) - base);
    return true;
}

// K1: 768 BALANCED blocks x 512 threads, every block ~96 KB of traffic,
// NO cross-block communication (R20 lesson: device-scope fences cost tens of µs):
//   0..255  : Wd COLUMN-quarter (t=bid>>2, q=bid&3): all 128 rows x 128 cols.
//             Column sums complete locally -> LDS combine -> ballot -> 2 tbits words.
//   256..511: LayerNorm (8 tokens/block) -> bf16 xn
//   512..767: Wu -> bf16 streaming copy
// Normal stores throughout (R18 lesson: consumers re-read these from L2).
__global__ __launch_bounds__(512) void k_prep(const float* __restrict__ x,
                                              const float* __restrict__ gamma,
                                              const float* __restrict__ beta,
                                              const float* __restrict__ Wd,
                                              const float* __restrict__ Wu,
                                              unsigned short* __restrict__ wd_b,
                                              unsigned short* __restrict__ wu_b,
                                              unsigned short* __restrict__ xn_b,
                                              u64* __restrict__ tbits,
                                              int* __restrict__ counts) {
    int bid = blockIdx.x;
    int tid = threadIdx.x;
    int lane = tid & 63;
    int wv = tid >> 6;
    if (bid < 256) {
        int t = bid >> 2, q = bid & 3;     // q = column quarter (cols q*128 .. q*128+127)
        if (bid == 0 && tid < NTILES) counts[tid] = 0;
        int r0 = tid >> 5;                 // row slice 0..15 -> rows r0*8 .. r0*8+7
        int c4 = tid & 31;                 // col group: cols q*128 + c4*4 .. +3
        const float* wp = Wd + ((size_t)t * DHID + r0 * 8) * DIM + q * 128 + c4 * 4;
        unsigned short* bp = wd_b + ((size_t)t * DHID + r0 * 8) * DIM + q * 128 + c4 * 4;
        float4 v[8];
        #pragma unroll
        for (int k = 0; k < 8; ++k) v[k] = *(const float4*)(wp + (size_t)k * DIM);
        float4 a = {0.f, 0.f, 0.f, 0.f};
        #pragma unroll
        for (int k = 0; k < 8; ++k) {
            u16x4 h = {bf16bits(v[k].x), bf16bits(v[k].y), bf16bits(v[k].z), bf16bits(v[k].w)};
            *(u16x4*)(bp + (size_t)k * DIM) = h;
            a.x += v[k].x; a.y += v[k].y; a.z += v[k].z; a.w += v[k].w;
        }
        __shared__ float ps[16][128];
        *(float4*)&ps[r0][c4 * 4] = a;
        __syncthreads();
        if (tid < 128) {                   // waves 0,1: column totals + ballot
            float s = 0.f;
            #pragma unroll
            for (int k = 0; k < 16; ++k) s += ps[k][tid];
            u64 b = __ballot(s < 0.f);     // wave wv covers cols q*128 + wv*64 + lane
            if (lane == 0) tbits[t * 8 + q * 2 + wv] = b;
        }
    } else if (bid < 512) {
        int n = (bid - 256) * 8 + wv;
        const float* xr = x + (size_t)n * DIM;
        float v[8];
        float sum = 0.f;
        #pragma unroll
        for (int j = 0; j < 8; ++j) { float t = xr[lane + 64 * j]; v[j] = t; sum += t; }
        #pragma unroll
        for (int off = 32; off; off >>= 1) sum += __shfl_xor(sum, off);
        float mu = sum * (1.f / DIM);
        float sq = 0.f;
        #pragma unroll
        for (int j = 0; j < 8; ++j) { float t = v[j] - mu; sq += t * t; }
        #pragma unroll
        for (int off = 32; off; off >>= 1) sq += __shfl_xor(sq, off);
        float rs = rsqrtf(sq * (1.f / DIM) + LN_EPS);
        #pragma unroll
        for (int j = 0; j < 8; ++j) {
            int d = lane + 64 * j;
            float xv = (v[j] - mu) * rs * gamma[d] + beta[d];
            xn_b[(size_t)n * DIM + d] = bf16bits(xv);
        }
    } else {
        // Wu streaming cvt: 256 blocks x 16384 floats
        size_t basei = (size_t)(bid - 512) * 16384;
        #pragma unroll
        for (int k = 0; k < 4; ++k) {
            size_t off = basei + (size_t)tid * 8 + (size_t)k * 4096;
            *(bf16x8*)(wu_b + off) = cvt8(Wu + off);
        }
    }
}

// K2: routing, one token per wave. Cluster majority bits computed inline from tbits
// via bitwise CSA (lane k handles cluster k>>3, word k&7). Integer scores == exact
// f32 argmax with first-index tie-break.
__global__ __launch_bounds__(256) void k_route(const unsigned short* __restrict__ xn_b,
                                               const u64* __restrict__ tbits,
                                               int* __restrict__ counts,
                                               int* __restrict__ list) {
    int n = blockIdx.x * 4 + (threadIdx.x >> 6);
    int lane = threadIdx.x & 63;
    u64 xb[8];
    #pragma unroll
    for (int j = 0; j < 8; ++j) {
        unsigned short u = xn_b[(size_t)n * DIM + lane + 64 * j];
        xb[j] = __ballot((u & 0x8000u) != 0 && (u & 0x7fffu) != 0);  // strictly negative
    }
    const u64* tb = tbits + lane * 8;
    int ts = 0;
    #pragma unroll
    for (int j = 0; j < 8; ++j) ts += __popcll(xb[j] ^ tb[j]);
    int tscore = DIM - 2 * ts;

    int c = lane >> 3, jw = lane & 7;
    u64 x0 = tbits[(c * TPC + 0) * 8 + jw], x1 = tbits[(c * TPC + 1) * 8 + jw];
    u64 x2 = tbits[(c * TPC + 2) * 8 + jw], x3 = tbits[(c * TPC + 3) * 8 + jw];
    u64 x4 = tbits[(c * TPC + 4) * 8 + jw], x5 = tbits[(c * TPC + 5) * 8 + jw];
    u64 x6 = tbits[(c * TPC + 6) * 8 + jw], x7 = tbits[(c * TPC + 7) * 8 + jw];
    u64 s0 = x0 ^ x1 ^ x2, c0 = maj3(x0, x1, x2);
    u64 s1 = x3 ^ x4 ^ x5, c1 = maj3(x3, x4, x5);
    u64 s2 = x6 ^ x7,      c2 = x6 & x7;
    u64 t0 = s0 ^ s1 ^ s2, t1 = maj3(s0, s1, s2);
    u64 p = c0 ^ c1, q = c0 & c1;
    u64 r = c2 ^ t1, s_ = c2 & t1;
    u64 S0 = p ^ r, car = p & r;
    u64 W0 = (q ^ s_) ^ car;
    u64 W1 = (q & s_) | (car & (q ^ s_));
    u64 cbit = W1 | (W0 & (S0 | t0));
    u64 cmsk = ~(W0 & ~W1 & ~S0 & ~t0);
    int psc = __popcll(cmsk) - 2 * __popcll((xb[jw] ^ cbit) & cmsk);
    psc += __shfl_xor(psc, 1);
    psc += __shfl_xor(psc, 2);
    psc += __shfl_xor(psc, 4);

    int bc = 0, best = __shfl(psc, 0);
    #pragma unroll
    for (int k = 1; k < NCLUST; ++k) {
        int v = __shfl(psc, k * 8);
        if (v > best) { best = v; bc = k; }
    }
    int bt = bc * TPC, bts = __shfl(tscore, bc * TPC);
    #pragma unroll
    for (int k = 1; k < TPC; ++k) {
        int v = __shfl(tscore, bc * TPC + k);
        if (v > bts) { bts = v; bt = bc * TPC + k; }
    }
    if (lane == 0) {
        int slot = atomicAdd(&counts[bt], 1);
        list[(size_t)bt * NTOK + slot] = n;
    }
}

// K3: fused down+spline+up, deep-prefetch variant.
__global__ __launch_bounds__(512, 1) void k_ffn(const float* __restrict__ x,
                                                const unsigned short* __restrict__ xn_b,
                                                const unsigned short* __restrict__ wd_b,
                                                const float* __restrict__ sb,
                                                const float* __restrict__ ss,
                                                const unsigned short* __restrict__ wu_b,
                                                const float* __restrict__ scale,
                                                const int* __restrict__ counts,
                                                const int* __restrict__ list,
                                                float* __restrict__ out) {
    int tid = threadIdx.x;
    int lane = tid & 63;
    int wv = tid >> 6;
    int cb = ((int)blockIdx.x & 7) * (NCHUNK_MAX / 8) + ((int)blockIdx.x >> 3);
    int t, base, m;
    if (!route_chunk(counts, lane, cb, t, base, m)) return;   // block-uniform exit

    __shared__ __align__(16) unsigned short hsl[TB * DHID];   // bf16, XOR-swizzled

    int mrow = lane & 15;
    int ko = (lane >> 4) * 8;
    int tokm = list[(size_t)t * NTOK + base + min(mrow, m - 1)];

    // ---- down: load ALL operands first (32 b128 in flight), then MFMA ----
    const unsigned short* xr = xn_b + (size_t)tokm * DIM;
    const unsigned short* wr = wd_b + ((size_t)t * DHID + wv * 16 + mrow) * DIM;
    bf16x8 wreg[16], areg[16];
    #pragma unroll
    for (int kk = 0; kk < 16; ++kk) {
        int d = kk * 32 + ko;
        wreg[kk] = *(const bf16x8*)(wr + d);
        areg[kk] = *(const bf16x8*)(xr + d);
    }
    f32x4 acc0 = {0.f, 0.f, 0.f, 0.f}, acc1 = acc0;
    #pragma unroll
    for (int kk = 0; kk < 8; ++kk) {
        acc0 = __builtin_amdgcn_mfma_f32_16x16x32_bf16(areg[2 * kk], wreg[2 * kk], acc0, 0, 0, 0);
        acc1 = __builtin_amdgcn_mfma_f32_16x16x32_bf16(areg[2 * kk + 1], wreg[2 * kk + 1], acc1, 0, 0, 0);
    }
    f32x4 acc = acc0 + acc1;

    // prefetch ALL up-phase Wu-bf16 rows (16 b128) before spline + barrier
    bf16x8 wupf[16];
    #pragma unroll
    for (int nt = 0; nt < 4; ++nt) {
        const unsigned short* wru = wu_b + ((size_t)t * DIM + wv * 64 + nt * 16 + mrow) * DHID;
        #pragma unroll
        for (int kk = 0; kk < 4; ++kk)
            wupf[nt * 4 + kk] = *(const bf16x8*)(wru + kk * 32 + ko);
    }

    // prefetch residual x gather (16 scalar f32 per thread; rows tr, cols d)
    int tokr[4];
    #pragma unroll
    for (int r = 0; r < 4; ++r) tokr[r] = __shfl(tokm, (lane >> 4) * 4 + r);
    float xpf[4][4];
    #pragma unroll
    for (int r = 0; r < 4; ++r) {
        #pragma unroll
        for (int nt = 0; nt < 4; ++nt)
            xpf[r][nt] = x[(size_t)tokr[r] * DIM + wv * 64 + nt * 16 + mrow];
    }

    // spline on C fragments -> LDS (rows tr>=m hold duplicated last token: valid bytes)
    int dh = wv * 16 + mrow;
    const float* sbt = sb + ((size_t)t * DHID + dh) * GRID_SZ;
    const float* sst = ss + ((size_t)t * DHID + dh) * GRID_SZ;
    #pragma unroll
    for (int r = 0; r < 4; ++r) {
        int tr = (lane >> 4) * 4 + r;
        float h = acc[r];
        float hn = 1.f / (1.f + expf(-h));
        float g = hn * (float)GRID_SZ;
        int idx = (int)g;
        idx = idx > GRID_SZ - 1 ? GRID_SZ - 1 : idx;
        float lp = g - (float)idx;
        float val = sbt[idx] + sst[idx] * lp;
        hsl[(tr * DHID + dh) ^ ((tr & 7) << 3)] = bf16bits(val);
    }
    __syncthreads();

    // ---- up: d-slice wv (4 independent n-tiles x 4 MFMA, K=128) ----
    float sc_t = scale[t];
    bf16x8 a2[4];
    #pragma unroll
    for (int kk = 0; kk < 4; ++kk)
        a2[kk] = *(const bf16x8*)&hsl[(mrow * DHID + kk * 32 + ko) ^ ((mrow & 7) << 3)];
    #pragma unroll
    for (int nt = 0; nt < 4; ++nt) {
        int d = wv * 64 + nt * 16 + mrow;
        f32x4 au = {0.f, 0.f, 0.f, 0.f};
        #pragma unroll
        for (int kk = 0; kk < 4; ++kk)
            au = __builtin_amdgcn_mfma_f32_16x16x32_bf16(a2[kk], wupf[nt * 4 + kk], au, 0, 0, 0);
        #pragma unroll
        for (int r = 0; r < 4; ++r) {
            int tr = (lane >> 4) * 4 + r;
            if (tr < m) {
                size_t o = (size_t)tokr[r] * DIM + d;
                out[o] = xpf[r][nt] + au[r] * sc_t;
            }
        }
    }
}

extern "C" void kernel_launch(void* const* d_in, const int* in_sizes, int n_in,
                              void* d_out, int out_size, void* d_ws, size_t ws_size,
                              hipStream_t stream) {
    const float* x     = (const float*)d_in[0];
    const float* gamma = (const float*)d_in[1];
    const float* beta  = (const float*)d_in[2];
    const float* Wd    = (const float*)d_in[3];
    const float* sb    = (const float*)d_in[4];
    const float* ss    = (const float*)d_in[5];
    const float* Wu    = (const float*)d_in[6];
    const float* scale = (const float*)d_in[7];
    float* out = (float*)d_out;

    // workspace layout
    u64*   tbits         = (u64*)d_ws;                             // 64*8 u64 = 4 KB
    int*   counts        = (int*)(tbits + NTILES * 8);             // 64 ints
    int*   list          = counts + NTILES;                        // 128K ints
    unsigned short* xn_b = (unsigned short*)(list + (size_t)NTILES * NTOK);  // 1M u16
    unsigned short* wd_b = xn_b + (size_t)NTOK * DIM;              // 4.19M u16
    unsigned short* wu_b = wd_b + (size_t)NTILES * DHID * DIM;     // 4.19M u16

    k_prep<<<768, 512, 0, stream>>>(x, gamma, beta, Wd, Wu, wd_b, wu_b, xn_b, tbits, counts);
    k_route<<<NTOK / 4, 256, 0, stream>>>(xn_b, tbits, counts, list);
    k_ffn<<<NCHUNK_MAX, 512, 0, stream>>>(x, xn_b, wd_b, sb, ss, wu_b, scale, counts, list, out);
}